// Round 18
// baseline (385.743 us; speedup 1.0000x reference)
//
#include <hip/hip_runtime.h>
#include <hip/hip_bf16.h>
#include <stdint.h>

#define NW 20
#define CD 512

typedef __attribute__((ext_vector_type(8))) short bhalf8;
typedef __attribute__((ext_vector_type(4))) float floatx4;

__device__ __forceinline__ uint16_t f2bf(float f){
    __hip_bfloat16 h = __float2bfloat16(f);
    return __builtin_bit_cast(uint16_t, h);
}
__device__ __forceinline__ float bf2f(uint16_t u){
    return __uint_as_float(((uint32_t)u) << 16);
}
__device__ __forceinline__ int hsw(int r){ return ((r >> 1) ^ (r >> 2)) & 7; }

// async global->LDS, 16 B per lane (wave-uniform LDS base + lane*16)
__device__ __forceinline__ void gload16(const void* g, void* l){
    __builtin_amdgcn_global_load_lds(
        (const __attribute__((address_space(1))) uint32_t*)g,
        (__attribute__((address_space(3))) uint32_t*)l, 16, 0, 0);
}

// legacy stub symbol kept (never launched)
__global__ void GroundTextBlock_context_49761491091856_kernel(int* p){ if (p) *p = 0; }

// ---------------- kprep: conv1_w f32 -> swizzled bf16 A-image (ws) ----------------
__global__ __launch_bounds__(256) void kprep(const float* __restrict__ w,
                                             uint16_t* __restrict__ warr){
    int ot = blockIdx.x >> 3, ks = blockIdx.x & 7;
    uint16_t* dst = warr + (size_t)blockIdx.x * 8192;
    for (int i = threadIdx.x; i < 8192; i += 256){
        int o = i >> 6, ke = i & 63;
        float v = w[(size_t)(ot * 128 + o) * 512 + ks * 64 + ke];
        int byteoff = o * 128 + ((((ke >> 3) ^ hsw(o)) << 4)) + ((ke & 7) << 1);
        dst[byteoff >> 1] = f2bf(v);
    }
}

// ---------------- kgemm: fused — direct fvisu read, bf16 staging, tile partials ----------------
// (round-12 proven version: 2-barrier loop, gload_lds A-stage, no prefetch)
__global__ __launch_bounds__(256) void kgemm(const float* __restrict__ fvisu,
                                             const uint16_t* __restrict__ warr,
                                             float* __restrict__ out0){
    __shared__ __align__(16) uint8_t Ab[16384];
    __shared__ __align__(16) uint8_t Bb[16384];
    __shared__ float tsum[CD];

    // XCD swizzle: the 4 o-tiles of one X-tile land on one XCD
    int lid = (int)((blockIdx.x & 7) * 512 + (blockIdx.x >> 3));
    int ot = lid & 3, jt = (lid >> 2) & 31, b = lid >> 7;

    int t = threadIdx.x;
    int lane = t & 63, wv = t >> 6;
    int wr = wv >> 1, wc = wv & 1;
    int l15 = lane & 15, l4 = lane >> 4;
    int cs0 = t >> 5, js = t & 31;
    int j0 = jt * 128;

    floatx4 acc[4][4];
    #pragma unroll
    for (int m = 0; m < 4; ++m)
        #pragma unroll
        for (int n = 0; n < 4; ++n)
            acc[m][n] = (floatx4){0.f, 0.f, 0.f, 0.f};

    for (int ks = 0; ks < 8; ++ks){
        if (ks) __syncthreads();
        // A stage: async linear 16 KB copy of pre-swizzled image
        {
            const uint8_t* asrc = (const uint8_t*)warr + (size_t)(ot * 8 + ks) * 16384;
            #pragma unroll
            for (int it = 0; it < 4; ++it){
                int lin = it * 4096 + t * 16;
                gload16(asrc + lin, Ab + lin);
            }
        }
        // B stage: load [c][j], 4x4 in-register transpose, bf16, swizzled write [j][c]
        int k0 = ks * 64;
        #pragma unroll
        for (int blk = 0; blk < 2; ++blk){
            int cs = cs0 + blk * 8;
            float va[4][4];
            #pragma unroll
            for (int ci = 0; ci < 4; ++ci){
                const float* src = fvisu + (((size_t)(b * CD + k0 + cs * 4 + ci)) << 12) + j0 + js * 4;
                float4 v = *(const float4*)src;
                va[ci][0] = v.x; va[ci][1] = v.y; va[ci][2] = v.z; va[ci][3] = v.w;
            }
            // tile_visu channel partials -> LDS (ot==0 only); one ks owns each channel
            if (ot == 0){
                #pragma unroll
                for (int ci = 0; ci < 4; ++ci){
                    float s = va[ci][0] + va[ci][1] + va[ci][2] + va[ci][3];
                    s += __shfl_xor(s, 1);  s += __shfl_xor(s, 2);
                    s += __shfl_xor(s, 4);  s += __shfl_xor(s, 8);
                    s += __shfl_xor(s, 16);
                    if ((lane & 31) == 0) tsum[k0 + cs * 4 + ci] = s;
                }
            }
            int unit = cs >> 1, half = cs & 1;
            #pragma unroll
            for (int jj = 0; jj < 4; ++jj){
                int j = js * 4 + jj;
                uint2 p;
                p.x = (uint32_t)f2bf(va[0][jj]) | ((uint32_t)f2bf(va[1][jj]) << 16);
                p.y = (uint32_t)f2bf(va[2][jj]) | ((uint32_t)f2bf(va[3][jj]) << 16);
                *(uint2*)(Bb + j * 128 + ((unit ^ hsw(j)) << 4) + half * 8) = p;
            }
        }
        __syncthreads();   // drains A gload_lds + orders B ds_writes
        // 2 K-slices x 4m x 4n MFMA 16x16x32 (swizzled fragment reads)
        #pragma unroll
        for (int ksl = 0; ksl < 2; ++ksl){
            bhalf8 af[4], bfr[4];
            #pragma unroll
            for (int m = 0; m < 4; ++m){
                int o = wr * 64 + m * 16 + l15;
                int u = (ksl * 4 + l4) ^ hsw(o);
                af[m] = *(const bhalf8*)(Ab + o * 128 + (u << 4));
            }
            #pragma unroll
            for (int n = 0; n < 4; ++n){
                int j = wc * 64 + n * 16 + l15;
                int u = (ksl * 4 + l4) ^ hsw(j);
                bfr[n] = *(const bhalf8*)(Bb + j * 128 + (u << 4));
            }
            #pragma unroll
            for (int m = 0; m < 4; ++m)
                #pragma unroll
                for (int n = 0; n < 4; ++n)
                    acc[m][n] = __builtin_amdgcn_mfma_f32_16x16x32_bf16(af[m], bfr[n], acc[m][n], 0, 0, 0);
        }
    }
    // tile partials: one coalesced 2 KB write per (b,jt) into row (b,jt) upper half
    if (ot == 0){
        __syncthreads();
        float* tp = out0 + (((size_t)(b * CD + jt)) << 12) + 2048;
        tp[t] = tsum[t];
        tp[t + 256] = tsum[t + 256];
    }
    // C store (bf16 staging in lower half of row slot)
    uint16_t* sbase = (uint16_t*)out0;
    #pragma unroll
    for (int m = 0; m < 4; ++m){
        #pragma unroll
        for (int r = 0; r < 4; ++r){
            int o = ot * 128 + wr * 64 + m * 16 + l4 * 4 + r;
            uint16_t* row = sbase + ((size_t)(b * CD + o) << 13);
            #pragma unroll
            for (int n = 0; n < 4; ++n)
                row[j0 + wc * 64 + n * 16 + l15] = f2bf(acc[m][n][r]);
        }
    }
}

// ---------------- kattn: 1024-thread version — 4x shorter serial dot chains ----------------
// o = t>>2, q = t&3: each thread dots a 128-c quarter; quarters combined via shfl_xor(1,2)
// (the 4 q-lanes of an o are adjacent lanes). FiLM: one k per thread (1024 k's).
__global__ __launch_bounds__(1024) void kattn(
    const float* __restrict__ fword, const float* __restrict__ cscore,
    const float* __restrict__ amw, const float* __restrict__ amb,
    const float* __restrict__ asw, const float* __restrict__ asb,
    const float* __restrict__ gw, const float* __restrict__ gb,
    const int* __restrict__ wmask, const float* __restrict__ out0,
    float* __restrict__ out1, float* __restrict__ out2,
    float* __restrict__ gam_arr, float* __restrict__ bet_arr)
{
    int b = blockIdx.x, t = threadIdx.x;
    __shared__ __align__(16) float fws[NW][CD];    // 40960 B
    __shared__ __align__(16) float tl[CD];
    __shared__ __align__(16) float al[CD];
    __shared__ float css[NW];
    __shared__ int wm[NW];
    __shared__ float wred[16][NW];                 // 16 waves
    __shared__ float sc[NW];
    __shared__ float ms[NW];

    // tile_visu finalize: sum 32 jt-partial slots (upper halves of rows o=0..31)
    if (t < CD){
        int c = t;
        float s = 0.f;
        #pragma unroll 8
        for (int j2 = 0; j2 < 32; ++j2)
            s += out0[(((size_t)(b * CD + j2)) << 12) + 2048 + c];
        tl[c] = s * (1.f / 4096.f);
    }
    {
        const float4* src = (const float4*)(fword + (size_t)b * NW * CD);
        float4* dst = (float4*)&fws[0][0];
        for (int i = t; i < NW * CD / 4; i += 1024) dst[i] = src[i];
    }
    if (t < NW){ css[t] = cscore[b * NW + t]; wm[t] = wmask[b * NW + t]; }
    __syncthreads();

    // attn_feat pre-activation: thread (o=t>>2, q=t&3) dots c in [q*128, q*128+128)
    int o = t >> 2, q = t & 3, c0 = q * 128;
    float a[NW];
    #pragma unroll
    for (int n = 0; n < NW; ++n) a[n] = 0.f;
    {
        const float4* wrp = (const float4*)(amw + (size_t)o * CD + c0);
        for (int c4 = 0; c4 < 32; ++c4){
            float4 wvv = wrp[c4];
            float4 tv = *(const float4*)(tl + c0 + c4 * 4);
            float wtx = wvv.x * tv.x, wty = wvv.y * tv.y, wtz = wvv.z * tv.z, wtw = wvv.w * tv.w;
            #pragma unroll
            for (int n = 0; n < NW; ++n){
                const float4 f = *(const float4*)(&fws[n][c0 + c4 * 4]);
                a[n] += wtx * f.x + wty * f.y + wtz * f.z + wtw * f.w;
            }
        }
    }
    // combine quarters (adjacent lanes), tanh, zero q!=0, reduce 16 o's per wave
    {
        float aswo = asw[o], ambo = amb[o];
        int wvi = t >> 6;
        #pragma unroll
        for (int n = 0; n < NW; ++n){
            float full = a[n] + __shfl_xor(a[n], 1);
            full += __shfl_xor(full, 2);               // full 512-c dot on all 4 q-lanes
            float fo = aswo * tanhf(full * css[n] + ambo);
            if (q) fo = 0.f;                           // count each o once
            fo += __shfl_xor(fo, 4);  fo += __shfl_xor(fo, 8);
            fo += __shfl_xor(fo, 16); fo += __shfl_xor(fo, 32);
            if ((t & 63) == 0) wred[wvi][n] = fo;
        }
    }
    __syncthreads();
    if (t < NW){
        float s = asb[0];
        #pragma unroll
        for (int w16 = 0; w16 < 16; ++w16) s += wred[w16][t];
        sc[t] = s;
        out2[b * NW + t] = s;
    }
    __syncthreads();
    // mask softmax on wave 0
    if (t < 64){
        float logit = (t < NW) ? sc[t] * 10.f : -1e30f;
        float mx = logit;
        #pragma unroll
        for (int m = 32; m >= 1; m >>= 1) mx = fmaxf(mx, __shfl_xor(mx, m));
        float e = (t < NW) ? expf(logit - mx) : 0.f;
        float den = e;
        #pragma unroll
        for (int m = 32; m >= 1; m >>= 1) den += __shfl_xor(den, m);
        float p = e / den;
        float m0 = (t > 0 && t < NW) ? (float)wm[t] : 0.f;
        float cnt = m0;
        #pragma unroll
        for (int m = 32; m >= 1; m >>= 1) cnt += __shfl_xor(cnt, m);
        int sidx = (int)(cnt + 0.5f);
        float m1 = (t == sidx) ? 0.f : m0;
        float msv = p * m1;
        float d2 = msv;
        #pragma unroll
        for (int m = 32; m >= 1; m >>= 1) d2 += __shfl_xor(d2, m);
        d2 += 1e-8f;
        if (t < NW) ms[t] = msv / d2;
    }
    __syncthreads();
    // attn_lang + out1 = ms * fw  [b][d][n] (f32): first 512 threads, one d each
    if (t < CD){
        int d = t;
        float acc_ = 0.f;
        float pk[NW];
        #pragma unroll
        for (int n = 0; n < NW; ++n){
            float v = ms[n] * fws[n][d];
            acc_ += v;
            pk[n] = v;
        }
        al[d] = acc_;
        float4* dst = (float4*)(out1 + (size_t)b * CD * NW + (size_t)d * NW);
        #pragma unroll
        for (int i = 0; i < NW / 4; ++i)
            dst[i] = make_float4(pk[i * 4], pk[i * 4 + 1], pk[i * 4 + 2], pk[i * 4 + 3]);
    }
    __syncthreads();
    // FiLM: one gamma_w row per thread (k = t, 0..1023)
    {
        int k = t;
        const float4* gr = (const float4*)(gw + (size_t)k * CD);
        float s = gb[k];
        for (int c4 = 0; c4 < 128; ++c4){
            float4 g4 = gr[c4];
            float4 a4 = *(const float4*)(al + c4 * 4);
            s += g4.x * a4.x + g4.y * a4.y + g4.z * a4.z + g4.w * a4.w;
        }
        float tv = tanhf(s);
        if (k < CD) gam_arr[b * CD + k] = tv;
        else        bet_arr[b * CD + (k - CD)] = tv;
    }
}

// ---------------- knormstat: bf16-staged stats + instance-norm + FiLM + ReLU ----------------
__global__ __launch_bounds__(256) void knormstat(
    float* __restrict__ out0, const float* __restrict__ gam_arr,
    const float* __restrict__ bet_arr)
{
    int bo = blockIdx.x, t = threadIdx.x;
    const uint16_t* srow = (const uint16_t*)out0 + ((size_t)bo << 13);
    float x[16];
    float s = 0.f, q = 0.f;
    #pragma unroll
    for (int h = 0; h < 2; ++h){
        uint4 v = *(const uint4*)(srow + (size_t)(h * 256 + t) * 8);
        uint32_t w[4] = {v.x, v.y, v.z, v.w};
        #pragma unroll
        for (int i = 0; i < 4; ++i){
            float x0 = bf2f((uint16_t)(w[i] & 0xffffu));
            float x1 = bf2f((uint16_t)(w[i] >> 16));
            x[h * 8 + i * 2]     = x0;
            x[h * 8 + i * 2 + 1] = x1;
            s += x0 + x1; q += x0 * x0 + x1 * x1;
        }
    }
    #pragma unroll
    for (int m = 1; m <= 32; m <<= 1){ s += __shfl_xor(s, m); q += __shfl_xor(q, m); }
    __shared__ float ss[4], qq[4];
    if ((t & 63) == 0){ ss[t >> 6] = s; qq[t >> 6] = q; }
    __syncthreads();                                   // orders all reads before any write
    float S = ss[0] + ss[1] + ss[2] + ss[3];
    float Q = qq[0] + qq[1] + qq[2] + qq[3];
    float mu = S * (1.f / 4096.f);
    float var = Q * (1.f / 4096.f) - mu * mu;
    float rs = rsqrtf(var + 1e-5f);
    float g = gam_arr[bo], be = bet_arr[bo];
    float4* drow = (float4*)(out0 + ((size_t)bo << 12));
    #pragma unroll
    for (int h = 0; h < 2; ++h){
        #pragma unroll
        for (int gix = 0; gix < 2; ++gix){
            float4 w4;
            w4.x = fmaxf(0.f, g * ((x[h * 8 + gix * 4 + 0] - mu) * rs) + be);
            w4.y = fmaxf(0.f, g * ((x[h * 8 + gix * 4 + 1] - mu) * rs) + be);
            w4.z = fmaxf(0.f, g * ((x[h * 8 + gix * 4 + 2] - mu) * rs) + be);
            w4.w = fmaxf(0.f, g * ((x[h * 8 + gix * 4 + 3] - mu) * rs) + be);
            drow[(size_t)(h * 256 + t) * 2 + gix] = w4;
        }
    }
}

extern "C" void kernel_launch(void* const* d_in, const int* in_sizes, int n_in,
                              void* d_out, int out_size, void* d_ws, size_t ws_size,
                              hipStream_t stream)
{
    const float* fvisu  = (const float*)d_in[0];
    const float* fword  = (const float*)d_in[1];
    const float* cscore = (const float*)d_in[2];
    const float* amw    = (const float*)d_in[3];
    const float* amb    = (const float*)d_in[4];
    const float* asw    = (const float*)d_in[5];
    const float* asb    = (const float*)d_in[6];
    const float* gw     = (const float*)d_in[7];
    const float* gb     = (const float*)d_in[8];
    const float* cw     = (const float*)d_in[9];
    // d_in[10] = conv1_b: exactly cancelled by instance-norm mean subtraction
    const int* wmask    = (const int*)d_in[11];

    float* out0 = (float*)d_out;                          // fmodu [32,512,64,64] f32
    float* out1 = out0 + (size_t)67108864;                // attn_lang_my f32
    float* out2 = out1 + (size_t)327680;                  // attn_score f32

    // ws footprint within the proven-safe 983040 bytes
    uint8_t* ws = (uint8_t*)d_ws;
    uint16_t* warr = (uint16_t*)ws;                       //      0 .. 524288
    float* gam_arr = (float*)(ws + 524288);               // .. 589824
    float* bet_arr = (float*)(ws + 589824);               // .. 655360

    kprep<<<32, 256, 0, stream>>>(cw, warr);
    kgemm<<<4096, 256, 0, stream>>>(fvisu, warr, out0);
    kattn<<<32, 1024, 0, stream>>>(fword, cscore, amw, amb, asw, asb, gw, gb, wmask,
                                   out0, out1, out2, gam_arr, bet_arr);
    knormstat<<<16384, 256, 0, stream>>>(out0, gam_arr, bet_arr);
}

// Round 19
// 360.292 us; speedup vs baseline: 1.0706x; 1.0706x over previous
//
#include <hip/hip_runtime.h>
#include <hip/hip_bf16.h>
#include <stdint.h>

#define NW 20
#define CD 512

typedef __attribute__((ext_vector_type(8))) short bhalf8;
typedef __attribute__((ext_vector_type(4))) float floatx4;

__device__ __forceinline__ uint16_t f2bf(float f){
    __hip_bfloat16 h = __float2bfloat16(f);
    return __builtin_bit_cast(uint16_t, h);
}
__device__ __forceinline__ float bf2f(uint16_t u){
    return __uint_as_float(((uint32_t)u) << 16);
}
__device__ __forceinline__ int hsw(int r){ return ((r >> 1) ^ (r >> 2)) & 7; }

// async global->LDS, 16 B per lane (wave-uniform LDS base + lane*16)
__device__ __forceinline__ void gload16(const void* g, void* l){
    __builtin_amdgcn_global_load_lds(
        (const __attribute__((address_space(1))) uint32_t*)g,
        (__attribute__((address_space(3))) uint32_t*)l, 16, 0, 0);
}

// legacy stub symbol kept (never launched)
__global__ void GroundTextBlock_context_49761491091856_kernel(int* p){ if (p) *p = 0; }

// ---------------- kprep: conv1_w f32 -> swizzled bf16 A-image (ws) ----------------
__global__ __launch_bounds__(256) void kprep(const float* __restrict__ w,
                                             uint16_t* __restrict__ warr){
    int ot = blockIdx.x >> 3, ks = blockIdx.x & 7;
    uint16_t* dst = warr + (size_t)blockIdx.x * 8192;
    for (int i = threadIdx.x; i < 8192; i += 256){
        int o = i >> 6, ke = i & 63;
        float v = w[(size_t)(ot * 128 + o) * 512 + ks * 64 + ke];
        int byteoff = o * 128 + ((((ke >> 3) ^ hsw(o)) << 4)) + ((ke & 7) << 1);
        dst[byteoff >> 1] = f2bf(v);
    }
}

// ---------------- kgemm: fused — direct fvisu read, bf16 staging, tile partials ----------------
// (round-12 proven version: 2-barrier loop, gload_lds A-stage, no prefetch)
__global__ __launch_bounds__(256) void kgemm(const float* __restrict__ fvisu,
                                             const uint16_t* __restrict__ warr,
                                             float* __restrict__ out0){
    __shared__ __align__(16) uint8_t Ab[16384];
    __shared__ __align__(16) uint8_t Bb[16384];
    __shared__ float tsum[CD];

    // XCD swizzle: the 4 o-tiles of one X-tile land on one XCD
    int lid = (int)((blockIdx.x & 7) * 512 + (blockIdx.x >> 3));
    int ot = lid & 3, jt = (lid >> 2) & 31, b = lid >> 7;

    int t = threadIdx.x;
    int lane = t & 63, wv = t >> 6;
    int wr = wv >> 1, wc = wv & 1;
    int l15 = lane & 15, l4 = lane >> 4;
    int cs0 = t >> 5, js = t & 31;
    int j0 = jt * 128;

    floatx4 acc[4][4];
    #pragma unroll
    for (int m = 0; m < 4; ++m)
        #pragma unroll
        for (int n = 0; n < 4; ++n)
            acc[m][n] = (floatx4){0.f, 0.f, 0.f, 0.f};

    for (int ks = 0; ks < 8; ++ks){
        if (ks) __syncthreads();
        // A stage: async linear 16 KB copy of pre-swizzled image
        {
            const uint8_t* asrc = (const uint8_t*)warr + (size_t)(ot * 8 + ks) * 16384;
            #pragma unroll
            for (int it = 0; it < 4; ++it){
                int lin = it * 4096 + t * 16;
                gload16(asrc + lin, Ab + lin);
            }
        }
        // B stage: load [c][j], 4x4 in-register transpose, bf16, swizzled write [j][c]
        int k0 = ks * 64;
        #pragma unroll
        for (int blk = 0; blk < 2; ++blk){
            int cs = cs0 + blk * 8;
            float va[4][4];
            #pragma unroll
            for (int ci = 0; ci < 4; ++ci){
                const float* src = fvisu + (((size_t)(b * CD + k0 + cs * 4 + ci)) << 12) + j0 + js * 4;
                float4 v = *(const float4*)src;
                va[ci][0] = v.x; va[ci][1] = v.y; va[ci][2] = v.z; va[ci][3] = v.w;
            }
            // tile_visu channel partials -> LDS (ot==0 only); one ks owns each channel
            if (ot == 0){
                #pragma unroll
                for (int ci = 0; ci < 4; ++ci){
                    float s = va[ci][0] + va[ci][1] + va[ci][2] + va[ci][3];
                    s += __shfl_xor(s, 1);  s += __shfl_xor(s, 2);
                    s += __shfl_xor(s, 4);  s += __shfl_xor(s, 8);
                    s += __shfl_xor(s, 16);
                    if ((lane & 31) == 0) tsum[k0 + cs * 4 + ci] = s;
                }
            }
            int unit = cs >> 1, half = cs & 1;
            #pragma unroll
            for (int jj = 0; jj < 4; ++jj){
                int j = js * 4 + jj;
                uint2 p;
                p.x = (uint32_t)f2bf(va[0][jj]) | ((uint32_t)f2bf(va[1][jj]) << 16);
                p.y = (uint32_t)f2bf(va[2][jj]) | ((uint32_t)f2bf(va[3][jj]) << 16);
                *(uint2*)(Bb + j * 128 + ((unit ^ hsw(j)) << 4) + half * 8) = p;
            }
        }
        __syncthreads();   // drains A gload_lds + orders B ds_writes
        // 2 K-slices x 4m x 4n MFMA 16x16x32 (swizzled fragment reads)
        #pragma unroll
        for (int ksl = 0; ksl < 2; ++ksl){
            bhalf8 af[4], bfr[4];
            #pragma unroll
            for (int m = 0; m < 4; ++m){
                int o = wr * 64 + m * 16 + l15;
                int u = (ksl * 4 + l4) ^ hsw(o);
                af[m] = *(const bhalf8*)(Ab + o * 128 + (u << 4));
            }
            #pragma unroll
            for (int n = 0; n < 4; ++n){
                int j = wc * 64 + n * 16 + l15;
                int u = (ksl * 4 + l4) ^ hsw(j);
                bfr[n] = *(const bhalf8*)(Bb + j * 128 + (u << 4));
            }
            #pragma unroll
            for (int m = 0; m < 4; ++m)
                #pragma unroll
                for (int n = 0; n < 4; ++n)
                    acc[m][n] = __builtin_amdgcn_mfma_f32_16x16x32_bf16(af[m], bfr[n], acc[m][n], 0, 0, 0);
        }
    }
    // tile partials: one coalesced 2 KB write per (b,jt) into row (b,jt) upper half
    if (ot == 0){
        __syncthreads();
        float* tp = out0 + (((size_t)(b * CD + jt)) << 12) + 2048;
        tp[t] = tsum[t];
        tp[t + 256] = tsum[t + 256];
    }
    // C store (bf16 staging in lower half of row slot)
    uint16_t* sbase = (uint16_t*)out0;
    #pragma unroll
    for (int m = 0; m < 4; ++m){
        #pragma unroll
        for (int r = 0; r < 4; ++r){
            int o = ot * 128 + wr * 64 + m * 16 + l4 * 4 + r;
            uint16_t* row = sbase + ((size_t)(b * CD + o) << 13);
            #pragma unroll
            for (int n = 0; n < 4; ++n)
                row[j0 + wc * 64 + n * 16 + l15] = f2bf(acc[m][n][r]);
        }
    }
}

// ---------------- kattn: tile-partial reduce + attention + mask softmax + FiLM ----------------
__global__ __launch_bounds__(256) void kattn(
    const float* __restrict__ fword, const float* __restrict__ cscore,
    const float* __restrict__ amw, const float* __restrict__ amb,
    const float* __restrict__ asw, const float* __restrict__ asb,
    const float* __restrict__ gw, const float* __restrict__ gb,
    const int* __restrict__ wmask, const float* __restrict__ out0,
    float* __restrict__ out1, float* __restrict__ out2,
    float* __restrict__ gam_arr, float* __restrict__ bet_arr)
{
    int b = blockIdx.x, t = threadIdx.x;
    __shared__ __align__(16) float fws[NW][CD];
    __shared__ __align__(16) float tl[CD];
    __shared__ __align__(16) float al[CD];
    __shared__ float css[NW];
    __shared__ int wm[NW];
    __shared__ float wred[4][NW];
    __shared__ float sc[NW];
    __shared__ float ms[NW];

    // tile_visu finalize: sum 32 jt-partial slots (upper halves of rows o=0..31)
    #pragma unroll
    for (int dd = 0; dd < 2; ++dd){
        int c = t + dd * 256;
        float s = 0.f;
        #pragma unroll 8
        for (int j2 = 0; j2 < 32; ++j2)
            s += out0[(((size_t)(b * CD + j2)) << 12) + 2048 + c];
        tl[c] = s * (1.f / 4096.f);
    }
    {
        const float4* src = (const float4*)(fword + (size_t)b * NW * CD);
        float4* dst = (float4*)&fws[0][0];
        for (int i = t; i < NW * CD / 4; i += 256) dst[i] = src[i];
    }
    if (t < NW){ css[t] = cscore[b * NW + t]; wm[t] = wmask[b * NW + t]; }
    __syncthreads();

    int o = t;
    float a[NW];
    #pragma unroll
    for (int n = 0; n < NW; ++n) a[n] = 0.f;
    {
        const float4* wrp = (const float4*)(amw + (size_t)o * CD);
        for (int c4 = 0; c4 < 128; ++c4){
            float4 wvv = wrp[c4];
            float4 tv = *(const float4*)(tl + c4 * 4);
            float wtx = wvv.x * tv.x, wty = wvv.y * tv.y, wtz = wvv.z * tv.z, wtw = wvv.w * tv.w;
            #pragma unroll
            for (int n = 0; n < NW; ++n){
                const float4 f = *(const float4*)(&fws[n][c4 * 4]);
                a[n] += wtx * f.x + wty * f.y + wtz * f.z + wtw * f.w;
            }
        }
    }
    {
        float aswo = asw[o], ambo = amb[o];
        #pragma unroll
        for (int n = 0; n < NW; ++n){
            float fo = aswo * tanhf(a[n] * css[n] + ambo);
            #pragma unroll
            for (int m = 1; m <= 32; m <<= 1) fo += __shfl_xor(fo, m);
            if ((t & 63) == 0) wred[t >> 6][n] = fo;
        }
    }
    __syncthreads();
    if (t < NW){
        float s = asb[0] + wred[0][t] + wred[1][t] + wred[2][t] + wred[3][t];
        sc[t] = s;
        out2[b * NW + t] = s;
    }
    __syncthreads();
    if (t < 64){
        float logit = (t < NW) ? sc[t] * 10.f : -1e30f;
        float mx = logit;
        #pragma unroll
        for (int m = 32; m >= 1; m >>= 1) mx = fmaxf(mx, __shfl_xor(mx, m));
        float e = (t < NW) ? expf(logit - mx) : 0.f;
        float den = e;
        #pragma unroll
        for (int m = 32; m >= 1; m >>= 1) den += __shfl_xor(den, m);
        float p = e / den;
        float m0 = (t > 0 && t < NW) ? (float)wm[t] : 0.f;
        float cnt = m0;
        #pragma unroll
        for (int m = 32; m >= 1; m >>= 1) cnt += __shfl_xor(cnt, m);
        int sidx = (int)(cnt + 0.5f);
        float m1 = (t == sidx) ? 0.f : m0;
        float msv = p * m1;
        float d2 = msv;
        #pragma unroll
        for (int m = 32; m >= 1; m >>= 1) d2 += __shfl_xor(d2, m);
        d2 += 1e-8f;
        if (t < NW) ms[t] = msv / d2;
    }
    __syncthreads();
    #pragma unroll
    for (int dd = 0; dd < 2; ++dd){
        int d = t + dd * 256;
        float acc_ = 0.f;
        float pk[NW];
        #pragma unroll
        for (int n = 0; n < NW; ++n){
            float v = ms[n] * fws[n][d];
            acc_ += v;
            pk[n] = v;
        }
        al[d] = acc_;
        float4* dst = (float4*)(out1 + (size_t)b * CD * NW + (size_t)d * NW);
        #pragma unroll
        for (int i = 0; i < NW / 4; ++i)
            dst[i] = make_float4(pk[i * 4], pk[i * 4 + 1], pk[i * 4 + 2], pk[i * 4 + 3]);
    }
    __syncthreads();
    #pragma unroll
    for (int kk = 0; kk < 4; ++kk){
        int k = kk * 256 + t;
        const float4* gr = (const float4*)(gw + (size_t)k * CD);
        float s = gb[k];
        for (int c4 = 0; c4 < 128; ++c4){
            float4 g4 = gr[c4];
            float4 a4 = *(const float4*)(al + c4 * 4);
            s += g4.x * a4.x + g4.y * a4.y + g4.z * a4.z + g4.w * a4.w;
        }
        float tv = tanhf(s);
        if (k < CD) gam_arr[b * CD + k] = tv;
        else        bet_arr[b * CD + (k - CD)] = tv;
    }
}

// ---------------- knormstat: bf16-staged stats + instance-norm + FiLM + ReLU ----------------
__global__ __launch_bounds__(256) void knormstat(
    float* __restrict__ out0, const float* __restrict__ gam_arr,
    const float* __restrict__ bet_arr)
{
    int bo = blockIdx.x, t = threadIdx.x;
    const uint16_t* srow = (const uint16_t*)out0 + ((size_t)bo << 13);
    float x[16];
    float s = 0.f, q = 0.f;
    #pragma unroll
    for (int h = 0; h < 2; ++h){
        uint4 v = *(const uint4*)(srow + (size_t)(h * 256 + t) * 8);
        uint32_t w[4] = {v.x, v.y, v.z, v.w};
        #pragma unroll
        for (int i = 0; i < 4; ++i){
            float x0 = bf2f((uint16_t)(w[i] & 0xffffu));
            float x1 = bf2f((uint16_t)(w[i] >> 16));
            x[h * 8 + i * 2]     = x0;
            x[h * 8 + i * 2 + 1] = x1;
            s += x0 + x1; q += x0 * x0 + x1 * x1;
        }
    }
    #pragma unroll
    for (int m = 1; m <= 32; m <<= 1){ s += __shfl_xor(s, m); q += __shfl_xor(q, m); }
    __shared__ float ss[4], qq[4];
    if ((t & 63) == 0){ ss[t >> 6] = s; qq[t >> 6] = q; }
    __syncthreads();                                   // orders all reads before any write
    float S = ss[0] + ss[1] + ss[2] + ss[3];
    float Q = qq[0] + qq[1] + qq[2] + qq[3];
    float mu = S * (1.f / 4096.f);
    float var = Q * (1.f / 4096.f) - mu * mu;
    float rs = rsqrtf(var + 1e-5f);
    float g = gam_arr[bo], be = bet_arr[bo];
    float4* drow = (float4*)(out0 + ((size_t)bo << 12));
    #pragma unroll
    for (int h = 0; h < 2; ++h){
        #pragma unroll
        for (int gix = 0; gix < 2; ++gix){
            float4 w4;
            w4.x = fmaxf(0.f, g * ((x[h * 8 + gix * 4 + 0] - mu) * rs) + be);
            w4.y = fmaxf(0.f, g * ((x[h * 8 + gix * 4 + 1] - mu) * rs) + be);
            w4.z = fmaxf(0.f, g * ((x[h * 8 + gix * 4 + 2] - mu) * rs) + be);
            w4.w = fmaxf(0.f, g * ((x[h * 8 + gix * 4 + 3] - mu) * rs) + be);
            drow[(size_t)(h * 256 + t) * 2 + gix] = w4;
        }
    }
}

extern "C" void kernel_launch(void* const* d_in, const int* in_sizes, int n_in,
                              void* d_out, int out_size, void* d_ws, size_t ws_size,
                              hipStream_t stream)
{
    const float* fvisu  = (const float*)d_in[0];
    const float* fword  = (const float*)d_in[1];
    const float* cscore = (const float*)d_in[2];
    const float* amw    = (const float*)d_in[3];
    const float* amb    = (const float*)d_in[4];
    const float* asw    = (const float*)d_in[5];
    const float* asb    = (const float*)d_in[6];
    const float* gw     = (const float*)d_in[7];
    const float* gb     = (const float*)d_in[8];
    const float* cw     = (const float*)d_in[9];
    // d_in[10] = conv1_b: exactly cancelled by instance-norm mean subtraction
    const int* wmask    = (const int*)d_in[11];

    float* out0 = (float*)d_out;                          // fmodu [32,512,64,64] f32
    float* out1 = out0 + (size_t)67108864;                // attn_lang_my f32
    float* out2 = out1 + (size_t)327680;                  // attn_score f32

    // ws footprint within the proven-safe 983040 bytes
    uint8_t* ws = (uint8_t*)d_ws;
    uint16_t* warr = (uint16_t*)ws;                       //      0 .. 524288
    float* gam_arr = (float*)(ws + 524288);               // .. 589824
    float* bet_arr = (float*)(ws + 589824);               // .. 655360

    kprep<<<32, 256, 0, stream>>>(cw, warr);
    kgemm<<<4096, 256, 0, stream>>>(fvisu, warr, out0);
    kattn<<<32, 256, 0, stream>>>(fword, cscore, amw, amb, asw, asb, gw, gb, wmask,
                                  out0, out1, out2, gam_arr, bet_arr);
    knormstat<<<16384, 256, 0, stream>>>(out0, gam_arr, bet_arr);
}